// Round 1
// baseline (240.474 us; speedup 1.0000x reference)
//
#include <hip/hip_runtime.h>

#define BB 8
#define CC 64
#define OO 64
#define NN 16384
#define MMODE 32
#define JJ 128
#define SFAC 64.0f

constexpr float TWO_PI_F = 6.28318530717958647692f;

// ws layout (floats): ft [B][J][C] at 0 (65536), A [B][O][J] at 65536 (65536)

__global__ __launch_bounds__(256) void fwd_kernel(
    const float* __restrict__ x, const float* __restrict__ x_in,
    float* __restrict__ ft) {
  __shared__ float bas[64 * 132];  // [n][j], pad to 132 (16B-aligned rows)
  __shared__ float xs[64 * 68];    // [n][c], pad to 68
  const int b = blockIdx.y;
  const int n0 = blockIdx.x * 512;
  const int t = threadIdx.x;
  const int tc = t >> 5;   // c = tc*8 + cc
  const int tj = t & 31;   // j = tj*4 + jj
  float acc[8][4];
#pragma unroll
  for (int i = 0; i < 8; ++i)
#pragma unroll
    for (int j = 0; j < 4; ++j) acc[i][j] = 0.f;

  const int lnB = t & 63;          // basis lane (distinct per lane -> no LDS write conflict)
  const int qB = t >> 6;           // 0..3
  const int branchB = qB >> 1, halfB = qB & 1;
  const int xc = t >> 2, xli = t & 3;  // x loader mapping

  for (int s = 0; s < 8; ++s) {
    const int ns = n0 + s * 64;
    __syncthreads();
    // ---- bases for 64 n (forward sign: exp(-i 2pi p m)) ----
    {
      const float p = x_in[((size_t)b * NN + ns + lnB) * 2 + branchB];
      float sr, cr;
      __sincosf(-TWO_PI_F * p, &sr, &cr);
      float br = 1.f, bi = 0.f;
      if (halfB) {  // start at step^16 via 4 squarings
        float r = cr, q = sr;
#pragma unroll
        for (int k = 0; k < 4; ++k) { const float nr = r*r - q*q, ni = 2.f*r*q; r = nr; q = ni; }
        br = r; bi = q;
      }
      float* bp = &bas[lnB * 132 + branchB * 64 + halfB * 32];
#pragma unroll
      for (int m = 0; m < 16; ++m) {
        bp[2*m] = br; bp[2*m+1] = bi;
        const float nr = br*cr - bi*sr, ni = br*sr + bi*cr;
        br = nr; bi = ni;
      }
    }
    // ---- x tile: 64 c x 64 n, coalesced float4 global reads ----
    {
      const float* xp = &x[((size_t)b * CC + xc) * NN + ns];
#pragma unroll
      for (int k4 = 0; k4 < 4; ++k4) {
        const int nn = xli * 4 + k4 * 16;
        const float4 v = *(const float4*)&xp[nn];
        xs[(nn + 0) * 68 + xc] = v.x;
        xs[(nn + 1) * 68 + xc] = v.y;
        xs[(nn + 2) * 68 + xc] = v.z;
        xs[(nn + 3) * 68 + xc] = v.w;
      }
    }
    __syncthreads();
    // ---- accumulate: reduction index n2 is wave-uniform ----
#pragma unroll 2
    for (int n2 = 0; n2 < 64; ++n2) {
      const float4 bv = *(const float4*)&bas[n2 * 132 + tj * 4];
      const float4 xa = *(const float4*)&xs[n2 * 68 + tc * 8];
      const float4 xb = *(const float4*)&xs[n2 * 68 + tc * 8 + 4];
      const float xr[8] = {xa.x, xa.y, xa.z, xa.w, xb.x, xb.y, xb.z, xb.w};
#pragma unroll
      for (int cc2 = 0; cc2 < 8; ++cc2) {
        acc[cc2][0] += xr[cc2] * bv.x;
        acc[cc2][1] += xr[cc2] * bv.y;
        acc[cc2][2] += xr[cc2] * bv.z;
        acc[cc2][3] += xr[cc2] * bv.w;
      }
    }
  }
#pragma unroll
  for (int cc2 = 0; cc2 < 8; ++cc2)
#pragma unroll
    for (int jj2 = 0; jj2 < 4; ++jj2) {
      const int c = tc * 8 + cc2, j = tj * 4 + jj2;
      atomicAdd(&ft[((size_t)b * JJ + j) * CC + c], acc[cc2][jj2]);
    }
}

__global__ __launch_bounds__(64) void mix_kernel(
    const float* __restrict__ ft, const float* __restrict__ w1,
    const float* __restrict__ w2, float* __restrict__ A) {
  __shared__ float fre[64], fim[64];
  const int m = blockIdx.x, branch = blockIdx.y, b = blockIdx.z;
  const int o = threadIdx.x;
  const int jb = branch * 64 + 2 * m;
  fre[o] = ft[((size_t)b * JJ + jb) * CC + o];
  fim[o] = ft[((size_t)b * JJ + jb + 1) * CC + o];
  __syncthreads();
  const float* w = branch ? w2 : w1;  // [i][o][m][2]
  float ar = 0.f, ai = 0.f;
#pragma unroll 4
  for (int i = 0; i < 64; ++i) {
    const float wr = w[(((size_t)i * 64 + o) * MMODE + m) * 2 + 0];
    const float wi = w[(((size_t)i * 64 + o) * MMODE + m) * 2 + 1];
    ar += fre[i] * wr - fim[i] * wi;
    ai += fre[i] * wi + fim[i] * wr;
  }
  // fold scale S=64 and Re(): out = A_re*cos + A_im*sin
  A[((size_t)b * OO + o) * JJ + jb]     =  SFAC * ar;
  A[((size_t)b * OO + o) * JJ + jb + 1] = -SFAC * ai;
}

__global__ __launch_bounds__(256) void inv_kernel(
    const float* __restrict__ x_out, const float* __restrict__ A,
    float* __restrict__ out) {
  __shared__ float bas[128 * 68];  // [j][n]  (j-major: reduction index uniform)
  __shared__ float As[128 * 68];   // [j][o]
  const int b = blockIdx.y;
  const int n0 = blockIdx.x * 512;
  const int t = threadIdx.x;
  {
    const float* Ap = &A[(size_t)b * OO * JJ];
#pragma unroll
    for (int e = t; e < OO * JJ; e += 256) {
      const int o = e >> 7, j = e & 127;
      As[j * 68 + o] = Ap[e];
    }
  }
  const int to = t >> 4;  // o = to*4 + oo
  const int tn = t & 15;  // n = tn*4 + nn
  const int lnB = t & 63, qB = t >> 6;
  const int branchB = qB >> 1, halfB = qB & 1;

  for (int s = 0; s < 8; ++s) {
    const int ns = n0 + s * 64;
    __syncthreads();
    // ---- inverse bases (sign +): exp(+i 2pi p m) ----
    {
      const float p = x_out[((size_t)b * NN + ns + lnB) * 2 + branchB];
      float sr, cr;
      __sincosf(TWO_PI_F * p, &sr, &cr);
      float br = 1.f, bi = 0.f;
      if (halfB) {
        float r = cr, q = sr;
#pragma unroll
        for (int k = 0; k < 4; ++k) { const float nr = r*r - q*q, ni = 2.f*r*q; r = nr; q = ni; }
        br = r; bi = q;
      }
      const int jb = branchB * 64 + halfB * 32;
#pragma unroll
      for (int m2 = 0; m2 < 16; ++m2) {
        bas[(jb + 2*m2) * 68 + lnB] = br;
        bas[(jb + 2*m2 + 1) * 68 + lnB] = bi;
        const float nr = br*cr - bi*sr, ni = br*sr + bi*cr;
        br = nr; bi = ni;
      }
    }
    __syncthreads();
    float acc[4][4];
#pragma unroll
    for (int i = 0; i < 4; ++i)
#pragma unroll
      for (int j = 0; j < 4; ++j) acc[i][j] = 0.f;
#pragma unroll 2
    for (int j = 0; j < 128; ++j) {
      const float4 av = *(const float4*)&As[j * 68 + to * 4];
      const float4 bv = *(const float4*)&bas[j * 68 + tn * 4];
      acc[0][0] += av.x*bv.x; acc[0][1] += av.x*bv.y; acc[0][2] += av.x*bv.z; acc[0][3] += av.x*bv.w;
      acc[1][0] += av.y*bv.x; acc[1][1] += av.y*bv.y; acc[1][2] += av.y*bv.z; acc[1][3] += av.y*bv.w;
      acc[2][0] += av.z*bv.x; acc[2][1] += av.z*bv.y; acc[2][2] += av.z*bv.z; acc[2][3] += av.z*bv.w;
      acc[3][0] += av.w*bv.x; acc[3][1] += av.w*bv.y; acc[3][2] += av.w*bv.z; acc[3][3] += av.w*bv.w;
    }
#pragma unroll
    for (int oo2 = 0; oo2 < 4; ++oo2) {
      const float4 v = make_float4(acc[oo2][0], acc[oo2][1], acc[oo2][2], acc[oo2][3]);
      *(float4*)&out[((size_t)b * OO + to * 4 + oo2) * NN + ns + tn * 4] = v;
    }
  }
}

extern "C" void kernel_launch(void* const* d_in, const int* in_sizes, int n_in,
                              void* d_out, int out_size, void* d_ws, size_t ws_size,
                              hipStream_t stream) {
  const float* x     = (const float*)d_in[0];
  const float* x_in  = (const float*)d_in[1];
  const float* x_out = (const float*)d_in[2];
  const float* w1    = (const float*)d_in[3];
  const float* w2    = (const float*)d_in[4];
  float* out = (float*)d_out;
  float* ft = (float*)d_ws;
  float* A  = ft + (size_t)BB * JJ * CC;

  hipMemsetAsync(ft, 0, (size_t)BB * JJ * CC * sizeof(float), stream);
  fwd_kernel<<<dim3(NN / 512, BB), 256, 0, stream>>>(x, x_in, ft);
  mix_kernel<<<dim3(MMODE, 2, BB), 64, 0, stream>>>(ft, w1, w2, A);
  inv_kernel<<<dim3(NN / 512, BB), 256, 0, stream>>>(x_out, A, out);
}

// Round 2
// 121.833 us; speedup vs baseline: 1.9738x; 1.9738x over previous
//
#include <hip/hip_runtime.h>

#define BB 8
#define CC 64
#define OO 64
#define NN 16384
#define MMODE 32
#define JJ 128
#define SFAC 64.0f

constexpr float TWO_PI_F = 6.28318530717958647692f;

typedef __attribute__((ext_vector_type(8))) short short8;   // 8 bf16 = 4 VGPRs (MFMA A/B frag)
typedef __attribute__((ext_vector_type(4))) float f32x4;    // MFMA C/D frag

static __device__ __forceinline__ unsigned short f2bf(float f) {
  unsigned u = __float_as_uint(f);
  u += 0x7FFF + ((u >> 16) & 1);   // RTNE
  return (unsigned short)(u >> 16);
}
static __device__ __forceinline__ unsigned pack2(float a, float b) {
  return (unsigned)f2bf(a) | ((unsigned)f2bf(b) << 16);
}

// ws layout (floats): ft [B][J][C] at 0 (65536), A [B][O][J] at 65536 (65536)

// ---------------- forward NUFFT: ft[b,j,c] = sum_n bas[j,n] * x[c,n] ----------------
__global__ __launch_bounds__(256) void fwd_kernel(
    const float* __restrict__ x, const float* __restrict__ x_in,
    float* __restrict__ ft) {
  __shared__ __attribute__((aligned(16))) short bas[JJ * 72];   // [j][n] bf16, stride 72 (144B, 16B-mult)
  __shared__ __attribute__((aligned(16))) short xs[32 * 72];    // [c][n] bf16
  __shared__ __attribute__((aligned(16))) float ps[1024];       // x_in slab [512 n][2]
  const int t = threadIdx.x;
  const int b = blockIdx.z, chalf = blockIdx.y;
  const int n0 = blockIdx.x * 512;

  // stage coords for whole slab (coalesced)
  {
    const float4 v = *(const float4*)&x_in[((size_t)b * NN + n0) * 2 + t * 4];
    *(float4*)&ps[t * 4] = v;
  }
  // x loader mapping: 32 c rows x 64 n per micro-slab, 2 float4/thread
  const int xc = t >> 3, xng = t & 7;
  const float* xbase = x + ((size_t)(b * CC + chalf * 32 + xc)) * NN + n0 + xng * 4;
  float4 ra = *(const float4*)(xbase);
  float4 rb = *(const float4*)(xbase + 32);

  const int w = t >> 6, L = t & 63;
  const int q4 = L >> 4, l15 = L & 15;
  f32x4 acc[4];
#pragma unroll
  for (int i = 0; i < 4; ++i) acc[i] = (f32x4){0.f, 0.f, 0.f, 0.f};

  __syncthreads();  // ps visible

  for (int s = 0; s < 8; ++s) {
    // ---- stage x micro-slab (fp32 regs -> bf16 LDS) ----
    *(uint2*)&xs[xc * 72 + xng * 4]      = make_uint2(pack2(ra.x, ra.y), pack2(ra.z, ra.w));
    *(uint2*)&xs[xc * 72 + xng * 4 + 32] = make_uint2(pack2(rb.x, rb.y), pack2(rb.z, rb.w));
    if (s < 7) {  // prefetch next micro-slab early (overlaps basis gen + MFMA)
      ra = *(const float4*)(xbase + (s + 1) * 64);
      rb = *(const float4*)(xbase + (s + 1) * 64 + 32);
    }
    // ---- basis gen: direct sincos, rows j-major so writes are contiguous b128 ----
    // task tau -> (branch, mode m, n-octet ng); value exp(-i*2pi*p*m)
#pragma unroll
    for (int ti = 0; ti < 2; ++ti) {
      const int tau = t + ti * 256;
      const int ng = tau & 7, mm = tau >> 3;
      const int br = mm >> 5, m = mm & 31;
      const float fm = -TWO_PI_F * (float)m;
      union { unsigned short u[8]; uint4 v; } R, I;
#pragma unroll
      for (int k = 0; k < 8; ++k) {
        const float p = ps[(s * 64 + ng * 8 + k) * 2 + br];
        float sv, cv;
        __sincosf(fm * p, &sv, &cv);   // sv = -sin(theta) = imag part
        R.u[k] = f2bf(cv);
        I.u[k] = f2bf(sv);
      }
      const int row = br * 64 + 2 * m;
      *(uint4*)&bas[row * 72 + ng * 8]       = R.v;
      *(uint4*)&bas[(row + 1) * 72 + ng * 8] = I.v;
    }
    __syncthreads();
    // ---- MFMA: 2 K-steps of 32 n; wave w owns j-tiles {2w,2w+1} x c-tiles {0,1} ----
#pragma unroll
    for (int ks = 0; ks < 2; ++ks) {
      const int ko = ks * 32 + q4 * 8;
      const short8 a0 = *(const short8*)&bas[(w * 32 + l15) * 72 + ko];
      const short8 a1 = *(const short8*)&bas[(w * 32 + 16 + l15) * 72 + ko];
      const short8 b0 = *(const short8*)&xs[l15 * 72 + ko];
      const short8 b1 = *(const short8*)&xs[(16 + l15) * 72 + ko];
      acc[0] = __builtin_amdgcn_mfma_f32_16x16x32_bf16(a0, b0, acc[0], 0, 0, 0);
      acc[1] = __builtin_amdgcn_mfma_f32_16x16x32_bf16(a0, b1, acc[1], 0, 0, 0);
      acc[2] = __builtin_amdgcn_mfma_f32_16x16x32_bf16(a1, b0, acc[2], 0, 0, 0);
      acc[3] = __builtin_amdgcn_mfma_f32_16x16x32_bf16(a1, b1, acc[3], 0, 0, 0);
    }
    __syncthreads();
  }
  // ---- epilogue: C/D layout col(c)=lane&15, row(j)=(lane>>4)*4+reg ----
  const int jb0 = w * 32 + q4 * 4;
  const int cb = chalf * 32 + l15;
#pragma unroll
  for (int ji = 0; ji < 2; ++ji)
#pragma unroll
    for (int ci = 0; ci < 2; ++ci) {
      const f32x4 v = acc[ji * 2 + ci];
#pragma unroll
      for (int r = 0; r < 4; ++r)
        atomicAdd(&ft[((size_t)b * JJ + jb0 + ji * 16 + r) * CC + cb + ci * 16], v[r]);
    }
}

// ---------------- mode mixing (tiny) ----------------
__global__ __launch_bounds__(64) void mix_kernel(
    const float* __restrict__ ft, const float* __restrict__ w1,
    const float* __restrict__ w2, float* __restrict__ A) {
  __shared__ float fre[64], fim[64];
  const int m = blockIdx.x, branch = blockIdx.y, b = blockIdx.z;
  const int o = threadIdx.x;
  const int jb = branch * 64 + 2 * m;
  fre[o] = ft[((size_t)b * JJ + jb) * CC + o];
  fim[o] = ft[((size_t)b * JJ + jb + 1) * CC + o];
  __syncthreads();
  const float* w = branch ? w2 : w1;  // [i][o][m][2]
  float ar = 0.f, ai = 0.f;
#pragma unroll 4
  for (int i = 0; i < 64; ++i) {
    const float wr = w[(((size_t)i * 64 + o) * MMODE + m) * 2 + 0];
    const float wi = w[(((size_t)i * 64 + o) * MMODE + m) * 2 + 1];
    ar += fre[i] * wr - fim[i] * wi;
    ai += fre[i] * wi + fim[i] * wr;
  }
  // fold scale S=64 and Re(): out = A_re*cos + A_im*sin
  A[((size_t)b * OO + o) * JJ + jb]     =  SFAC * ar;
  A[((size_t)b * OO + o) * JJ + jb + 1] = -SFAC * ai;
}

// ---------------- inverse NUFFT: out[b,o,n] = sum_j A2[o,j] * bas[n,j] ----------------
__global__ __launch_bounds__(256) void inv_kernel(
    const float* __restrict__ x_out, const float* __restrict__ A,
    float* __restrict__ out) {
  __shared__ __attribute__((aligned(16))) short As_s[OO * 136];  // [o][j] bf16, stride 136 (272B)
  __shared__ __attribute__((aligned(16))) short basn[64 * 136];  // [n][j] bf16
  __shared__ __attribute__((aligned(16))) float psI[512];        // x_out slab [256 n][2]
  const int t = threadIdx.x;
  const int b = blockIdx.y;
  const int n0 = blockIdx.x * 256;

  if (t < 128) {
    const float4 v = *(const float4*)&x_out[((size_t)b * NN + n0) * 2 + t * 4];
    *(float4*)&psI[t * 4] = v;
  }
#pragma unroll
  for (int idx = t; idx < 2048; idx += 256) {   // A fp32 -> bf16 LDS, coalesced
    const int o = idx >> 5, j4 = idx & 31;
    const float4 v = *(const float4*)&A[((size_t)b * OO + o) * JJ + j4 * 4];
    *(uint2*)&As_s[o * 136 + j4 * 4] = make_uint2(pack2(v.x, v.y), pack2(v.z, v.w));
  }
  const int w = t >> 6, L = t & 63;
  const int q4 = L >> 4, l15 = L & 15;
  const int nl = t & 63, q = t >> 6, br = q >> 1, half = q & 1;
  const int ot0 = (w & 1) * 32;   // o rows: ot0 + {0..15, 16..31}
  const int nt0 = (w >> 1) * 32;  // n cols: nt0 + {0..15, 16..31}
  __syncthreads();

  for (int s = 0; s < 4; ++s) {
    // ---- basis gen: lane nl owns row n, recurrence over 16 modes, contiguous b128 writes ----
    {
      const float p = psI[(s * 64 + nl) * 2 + br];
      float s1, c1;
      __sincosf(TWO_PI_F * p, &s1, &c1);   // inverse sign: exp(+i*2pi*p*m)
      float brr = 1.f, bii = 0.f;
      if (half) {  // start at step^16 via 4 squarings
        float r = c1, qq = s1;
#pragma unroll
        for (int k = 0; k < 4; ++k) { const float nr = r*r - qq*qq, ni = 2.f*r*qq; r = nr; qq = ni; }
        brr = r; bii = qq;
      }
      short* bp = &basn[nl * 136 + br * 64 + half * 32];
#pragma unroll
      for (int g = 0; g < 4; ++g) {
        union { unsigned short u[8]; uint4 v; } P;
#pragma unroll
        for (int mi = 0; mi < 4; ++mi) {
          P.u[2 * mi]     = f2bf(brr);
          P.u[2 * mi + 1] = f2bf(bii);
          const float nr = brr * c1 - bii * s1, ni = brr * s1 + bii * c1;
          brr = nr; bii = ni;
        }
        *(uint4*)&bp[g * 8] = P.v;
      }
    }
    __syncthreads();
    f32x4 acc[4];
#pragma unroll
    for (int i = 0; i < 4; ++i) acc[i] = (f32x4){0.f, 0.f, 0.f, 0.f};
#pragma unroll
    for (int ks = 0; ks < 4; ++ks) {
      const int ko = ks * 32 + q4 * 8;
      const short8 a0 = *(const short8*)&As_s[(ot0 + l15) * 136 + ko];
      const short8 a1 = *(const short8*)&As_s[(ot0 + 16 + l15) * 136 + ko];
      const short8 b0 = *(const short8*)&basn[(nt0 + l15) * 136 + ko];
      const short8 b1 = *(const short8*)&basn[(nt0 + 16 + l15) * 136 + ko];
      acc[0] = __builtin_amdgcn_mfma_f32_16x16x32_bf16(a0, b0, acc[0], 0, 0, 0);
      acc[1] = __builtin_amdgcn_mfma_f32_16x16x32_bf16(a0, b1, acc[1], 0, 0, 0);
      acc[2] = __builtin_amdgcn_mfma_f32_16x16x32_bf16(a1, b0, acc[2], 0, 0, 0);
      acc[3] = __builtin_amdgcn_mfma_f32_16x16x32_bf16(a1, b1, acc[3], 0, 0, 0);
    }
    // ---- store: row o = ot0+oi*16+q4*4+r, col n = nt0+ni*16+l15 (64B segments) ----
    const int nbase = n0 + s * 64 + nt0 + l15;
#pragma unroll
    for (int oi = 0; oi < 2; ++oi)
#pragma unroll
      for (int ni = 0; ni < 2; ++ni) {
        const f32x4 v = acc[oi * 2 + ni];
#pragma unroll
        for (int r = 0; r < 4; ++r)
          out[((size_t)b * OO + ot0 + oi * 16 + q4 * 4 + r) * NN + nbase + ni * 16] = v[r];
      }
    __syncthreads();
  }
}

extern "C" void kernel_launch(void* const* d_in, const int* in_sizes, int n_in,
                              void* d_out, int out_size, void* d_ws, size_t ws_size,
                              hipStream_t stream) {
  const float* x     = (const float*)d_in[0];
  const float* x_in  = (const float*)d_in[1];
  const float* x_out = (const float*)d_in[2];
  const float* w1    = (const float*)d_in[3];
  const float* w2    = (const float*)d_in[4];
  float* out = (float*)d_out;
  float* ft = (float*)d_ws;
  float* A  = ft + (size_t)BB * JJ * CC;

  hipMemsetAsync(ft, 0, (size_t)BB * JJ * CC * sizeof(float), stream);
  fwd_kernel<<<dim3(32, 2, BB), 256, 0, stream>>>(x, x_in, ft);
  mix_kernel<<<dim3(MMODE, 2, BB), 64, 0, stream>>>(ft, w1, w2, A);
  inv_kernel<<<dim3(64, BB), 256, 0, stream>>>(x_out, A, out);
}

// Round 3
// 119.500 us; speedup vs baseline: 2.0123x; 1.0195x over previous
//
#include <hip/hip_runtime.h>

#define BB 8
#define CC 64
#define OO 64
#define NN 16384
#define MMODE 32
#define JJ 128
#define SFAC 64.0f

typedef __attribute__((ext_vector_type(8))) short short8;   // 8 bf16 = 4 VGPRs (MFMA A/B frag)
typedef __attribute__((ext_vector_type(4))) float f32x4;    // MFMA C/D frag

static __device__ __forceinline__ unsigned short f2bf(float f) {
  unsigned u = __float_as_uint(f);
  u += 0x7FFF + ((u >> 16) & 1);   // RTNE
  return (unsigned short)(u >> 16);
}
static __device__ __forceinline__ unsigned pack2(float a, float b) {
  return (unsigned)f2bf(a) | ((unsigned)f2bf(b) << 16);
}
// hardware sin/cos: v_sin_f32/v_cos_f32 take REVOLUTIONS (D = sin(2*pi*S0))
static __device__ __forceinline__ float sin2pi(float x) { return __builtin_amdgcn_sinf(x); }
static __device__ __forceinline__ float cos2pi(float x) { return __builtin_amdgcn_cosf(x); }

// ws layout (floats):
//   part [B][32 slabs][J][C] at 0            (2,097,152 floats, 8 MB)
//   A    [B][O][J]           at 2,097,152    (65,536 floats)

// ---------------- forward NUFFT: part[b,sl,j,c] = sum_{n in slab} bas[j,n]*x[c,n] ----------------
__global__ __launch_bounds__(256) void fwd_kernel(
    const float* __restrict__ x, const float* __restrict__ x_in,
    float* __restrict__ part) {
  __shared__ __attribute__((aligned(16))) short bas[JJ * 72];   // [j][n] bf16, stride 72
  __shared__ __attribute__((aligned(16))) short xs[32 * 72];    // [c][n] bf16
  __shared__ __attribute__((aligned(16))) float ps[1024];       // x_in slab [512 n][2]
  const int t = threadIdx.x;
  const int b = blockIdx.z, chalf = blockIdx.y, sl = blockIdx.x;
  const int n0 = sl * 512;

  // stage coords for whole slab (coalesced)
  {
    const float4 v = *(const float4*)&x_in[((size_t)b * NN + n0) * 2 + t * 4];
    *(float4*)&ps[t * 4] = v;
  }
  // x loader mapping: 32 c rows x 64 n per micro-slab, 2 float4/thread
  const int xc = t >> 3, xng = t & 7;
  const float* xbase = x + ((size_t)(b * CC + chalf * 32 + xc)) * NN + n0 + xng * 4;
  float4 ra = *(const float4*)(xbase);
  float4 rb = *(const float4*)(xbase + 32);

  const int w = t >> 6, L = t & 63;
  const int q4 = L >> 4, l15 = L & 15;
  f32x4 acc[4];
#pragma unroll
  for (int i = 0; i < 4; ++i) acc[i] = (f32x4){0.f, 0.f, 0.f, 0.f};

  __syncthreads();  // ps visible

  for (int s = 0; s < 8; ++s) {
    // ---- stage x micro-slab (fp32 regs -> bf16 LDS) ----
    *(uint2*)&xs[xc * 72 + xng * 4]      = make_uint2(pack2(ra.x, ra.y), pack2(ra.z, ra.w));
    *(uint2*)&xs[xc * 72 + xng * 4 + 32] = make_uint2(pack2(rb.x, rb.y), pack2(rb.z, rb.w));
    if (s < 7) {  // prefetch next micro-slab (overlaps basis gen + MFMA)
      ra = *(const float4*)(xbase + (s + 1) * 64);
      rb = *(const float4*)(xbase + (s + 1) * 64 + 32);
    }
    // ---- basis gen: exp(-i*2pi*m*p) via revolutions-native HW sin/cos ----
#pragma unroll
    for (int ti = 0; ti < 2; ++ti) {
      const int tau = t + ti * 256;
      const int ng = tau & 7, mm = tau >> 3;
      const int br = mm >> 5, m = mm & 31;
      const float fm = (float)m;
      union { unsigned short u[8]; uint4 v; } R, I;
#pragma unroll
      for (int k = 0; k < 8; ++k) {
        const float p = ps[(s * 64 + ng * 8 + k) * 2 + br];
        float rev = fm * p;
        rev -= floorf(rev);                 // v_fract-style reduction
        R.u[k] = f2bf(cos2pi(rev));         // real = cos(2pi m p)
        I.u[k] = f2bf(-sin2pi(rev));        // imag = -sin(2pi m p)
      }
      const int row = br * 64 + 2 * m;
      *(uint4*)&bas[row * 72 + ng * 8]       = R.v;
      *(uint4*)&bas[(row + 1) * 72 + ng * 8] = I.v;
    }
    __syncthreads();
    // ---- MFMA: 2 K-steps of 32 n; wave w owns j-tiles {2w,2w+1} x c-tiles {0,1} ----
#pragma unroll
    for (int ks = 0; ks < 2; ++ks) {
      const int ko = ks * 32 + q4 * 8;
      const short8 a0 = *(const short8*)&bas[(w * 32 + l15) * 72 + ko];
      const short8 a1 = *(const short8*)&bas[(w * 32 + 16 + l15) * 72 + ko];
      const short8 b0 = *(const short8*)&xs[l15 * 72 + ko];
      const short8 b1 = *(const short8*)&xs[(16 + l15) * 72 + ko];
      acc[0] = __builtin_amdgcn_mfma_f32_16x16x32_bf16(a0, b0, acc[0], 0, 0, 0);
      acc[1] = __builtin_amdgcn_mfma_f32_16x16x32_bf16(a0, b1, acc[1], 0, 0, 0);
      acc[2] = __builtin_amdgcn_mfma_f32_16x16x32_bf16(a1, b0, acc[2], 0, 0, 0);
      acc[3] = __builtin_amdgcn_mfma_f32_16x16x32_bf16(a1, b1, acc[3], 0, 0, 0);
    }
    __syncthreads();
  }
  // ---- epilogue: non-atomic partial store. C/D layout: col(c)=lane&15, row(j)=q4*4+reg ----
  float* pp = part + (size_t)(b * 32 + sl) * JJ * CC;
  const int jb0 = w * 32 + q4 * 4;
  const int cb = chalf * 32 + l15;
#pragma unroll
  for (int ji = 0; ji < 2; ++ji)
#pragma unroll
    for (int ci = 0; ci < 2; ++ci) {
      const f32x4 v = acc[ji * 2 + ci];
#pragma unroll
      for (int r = 0; r < 4; ++r)
        pp[(jb0 + ji * 16 + r) * CC + cb + ci * 16] = v[r];
    }
}

// ---------------- mode mixing + slab reduction ----------------
__global__ __launch_bounds__(256) void mix_kernel(
    const float* __restrict__ part, const float* __restrict__ w1,
    const float* __restrict__ w2, float* __restrict__ A) {
  __shared__ float red[8][64];
  __shared__ float fre[64], fim[64];
  const int m = blockIdx.x, branch = blockIdx.y, b = blockIdx.z;
  const int t = threadIdx.x;
  const int c = t & 63, g = t >> 6;
  const int jb = branch * 64 + 2 * m;
  // phase 1: reduce 32 slab partials for rows jb, jb+1
  float pre = 0.f, pim = 0.f;
#pragma unroll
  for (int k = 0; k < 8; ++k) {
    const int sl = g + 4 * k;
    const float* pp = part + (size_t)(b * 32 + sl) * JJ * CC;
    pre += pp[jb * CC + c];
    pim += pp[(jb + 1) * CC + c];
  }
  red[g * 2][c] = pre;
  red[g * 2 + 1][c] = pim;
  __syncthreads();
  if (t < 64) {
    fre[t] = red[0][t] + red[2][t] + red[4][t] + red[6][t];
    fim[t] = red[1][t] + red[3][t] + red[5][t] + red[7][t];
  }
  __syncthreads();
  // phase 2: complex GEMV over i, split 4 ways
  const float* w = branch ? w2 : w1;  // [i][o][m][2]
  const int o = c;
  float ar = 0.f, ai = 0.f;
#pragma unroll 4
  for (int ii = 0; ii < 16; ++ii) {
    const int i = g * 16 + ii;
    const float2 wv = *(const float2*)&w[(((size_t)i * 64 + o) * MMODE + m) * 2];
    ar += fre[i] * wv.x - fim[i] * wv.y;
    ai += fre[i] * wv.y + fim[i] * wv.x;
  }
  red[g * 2][o] = ar;
  red[g * 2 + 1][o] = ai;
  __syncthreads();
  if (t < 64) {
    const float sr = red[0][t] + red[2][t] + red[4][t] + red[6][t];
    const float si = red[1][t] + red[3][t] + red[5][t] + red[7][t];
    // fold scale S=64 and Re(): out = A_re*cos + A_im*sin
    *(float2*)&A[((size_t)b * OO + t) * JJ + jb] = make_float2(SFAC * sr, -SFAC * si);
  }
}

// ---------------- inverse NUFFT: out[b,o,n] = sum_j A2[o,j] * bas[n,j] ----------------
__global__ __launch_bounds__(256) void inv_kernel(
    const float* __restrict__ x_out, const float* __restrict__ A,
    float* __restrict__ out) {
  __shared__ __attribute__((aligned(16))) short As_s[OO * 136];  // [o][j] bf16, stride 136
  __shared__ __attribute__((aligned(16))) short basn[64 * 136];  // [n][j] bf16
  __shared__ __attribute__((aligned(16))) float psI[512];        // x_out slab [256 n][2]
  const int t = threadIdx.x;
  const int b = blockIdx.y;
  const int n0 = blockIdx.x * 256;

  if (t < 128) {
    const float4 v = *(const float4*)&x_out[((size_t)b * NN + n0) * 2 + t * 4];
    *(float4*)&psI[t * 4] = v;
  }
#pragma unroll
  for (int idx = t; idx < 2048; idx += 256) {   // A fp32 -> bf16 LDS, coalesced
    const int o = idx >> 5, j4 = idx & 31;
    const float4 v = *(const float4*)&A[((size_t)b * OO + o) * JJ + j4 * 4];
    *(uint2*)&As_s[o * 136 + j4 * 4] = make_uint2(pack2(v.x, v.y), pack2(v.z, v.w));
  }
  const int w = t >> 6, L = t & 63;
  const int q4 = L >> 4, l15 = L & 15;
  const int nl = t & 63, q = t >> 6, br = q >> 1, half = q & 1;
  const int ot0 = (w & 1) * 32;   // o rows: ot0 + {0..15, 16..31}
  const int nt0 = (w >> 1) * 32;  // n cols: nt0 + {0..15, 16..31}
  __syncthreads();

  for (int s = 0; s < 4; ++s) {
    // ---- basis gen: lane owns row n; exp(+i*2pi*m*p) by recurrence over m ----
    {
      const float p = psI[(s * 64 + nl) * 2 + br];
      const float fr = p - floorf(p);
      const float s1 = sin2pi(fr), c1 = cos2pi(fr);   // step = exp(+i*2pi*p)
      float brr = 1.f, bii = 0.f;
      if (half) {  // start at step^16 via 4 squarings
        float r = c1, qq = s1;
#pragma unroll
        for (int k = 0; k < 4; ++k) { const float nr = r*r - qq*qq, ni = 2.f*r*qq; r = nr; qq = ni; }
        brr = r; bii = qq;
      }
      short* bp = &basn[nl * 136 + br * 64 + half * 32];
#pragma unroll
      for (int g = 0; g < 4; ++g) {
        union { unsigned short u[8]; uint4 v; } P;
#pragma unroll
        for (int mi = 0; mi < 4; ++mi) {
          P.u[2 * mi]     = f2bf(brr);
          P.u[2 * mi + 1] = f2bf(bii);
          const float nr = brr * c1 - bii * s1, ni = brr * s1 + bii * c1;
          brr = nr; bii = ni;
        }
        *(uint4*)&bp[g * 8] = P.v;
      }
    }
    __syncthreads();
    f32x4 acc[4];
#pragma unroll
    for (int i = 0; i < 4; ++i) acc[i] = (f32x4){0.f, 0.f, 0.f, 0.f};
#pragma unroll
    for (int ks = 0; ks < 4; ++ks) {
      const int ko = ks * 32 + q4 * 8;
      const short8 a0 = *(const short8*)&As_s[(ot0 + l15) * 136 + ko];
      const short8 a1 = *(const short8*)&As_s[(ot0 + 16 + l15) * 136 + ko];
      const short8 b0 = *(const short8*)&basn[(nt0 + l15) * 136 + ko];
      const short8 b1 = *(const short8*)&basn[(nt0 + 16 + l15) * 136 + ko];
      acc[0] = __builtin_amdgcn_mfma_f32_16x16x32_bf16(a0, b0, acc[0], 0, 0, 0);
      acc[1] = __builtin_amdgcn_mfma_f32_16x16x32_bf16(a0, b1, acc[1], 0, 0, 0);
      acc[2] = __builtin_amdgcn_mfma_f32_16x16x32_bf16(a1, b0, acc[2], 0, 0, 0);
      acc[3] = __builtin_amdgcn_mfma_f32_16x16x32_bf16(a1, b1, acc[3], 0, 0, 0);
    }
    // ---- store: row o = ot0+oi*16+q4*4+r, col n = nt0+ni*16+l15 (64B segments) ----
    const int nbase = n0 + s * 64 + nt0 + l15;
#pragma unroll
    for (int oi = 0; oi < 2; ++oi)
#pragma unroll
      for (int ni = 0; ni < 2; ++ni) {
        const f32x4 v = acc[oi * 2 + ni];
#pragma unroll
        for (int r = 0; r < 4; ++r)
          out[((size_t)b * OO + ot0 + oi * 16 + q4 * 4 + r) * NN + nbase + ni * 16] = v[r];
      }
    __syncthreads();
  }
}

extern "C" void kernel_launch(void* const* d_in, const int* in_sizes, int n_in,
                              void* d_out, int out_size, void* d_ws, size_t ws_size,
                              hipStream_t stream) {
  const float* x     = (const float*)d_in[0];
  const float* x_in  = (const float*)d_in[1];
  const float* x_out = (const float*)d_in[2];
  const float* w1    = (const float*)d_in[3];
  const float* w2    = (const float*)d_in[4];
  float* out = (float*)d_out;
  float* part = (float*)d_ws;                       // [B][32][J][C]
  float* A = part + (size_t)BB * 32 * JJ * CC;      // [B][O][J]

  fwd_kernel<<<dim3(32, 2, BB), 256, 0, stream>>>(x, x_in, part);
  mix_kernel<<<dim3(MMODE, 2, BB), 256, 0, stream>>>(part, w1, w2, A);
  inv_kernel<<<dim3(64, BB), 256, 0, stream>>>(x_out, A, out);
}